// Round 7
// baseline (237.966 us; speedup 1.0000x reference)
//
#include <hip/hip_runtime.h>
#include <hip/hip_bf16.h>

#define IMG 28
#define KX 784             // true K = 28*28
#define KT 25              // k-tiles of 32 -> K padded to 800
#define NT 13              // n-tiles of 16 -> N padded to 208
#define NH 200
#define NOUT 10
#define HS 232             // LDS h row stride (bf16): 464 B, 16B-aligned rows
#define W1KT 7             // FC1 k-tiles (K=224)

typedef __attribute__((ext_vector_type(8))) short bf16x8;
typedef __attribute__((ext_vector_type(4))) float f32x4;

static __device__ __forceinline__ unsigned short bf16_bits(float v) {
    __hip_bfloat16 b = __float2bfloat16(v);
    return *(unsigned short*)&b;
}

static __device__ __forceinline__ bf16x8 cvt8(float4 lo, float4 hi) {
    bf16x8 r;
    r[0] = (short)bf16_bits(lo.x); r[1] = (short)bf16_bits(lo.y);
    r[2] = (short)bf16_bits(lo.z); r[3] = (short)bf16_bits(lo.w);
    r[4] = (short)bf16_bits(hi.x); r[5] = (short)bf16_bits(hi.y);
    r[6] = (short)bf16_bits(hi.z); r[7] = (short)bf16_bits(hi.w);
    return r;
}

// --- build W_eff (conv∘w0) and W1, packed in MFMA fragment order, 0-padded ---
// Bf [nt][kt][lane][j] = W_eff[nt*16+(lane&15)][kt*32+(lane>>4)*8+j]
// W1f[kt][lane][j]     = w1  [lane&15]         [kt*32+(lane>>4)*8+j]
__global__ void build_weights(const float* __restrict__ w0, const float* __restrict__ cw,
                              const float* __restrict__ w1,
                              __hip_bfloat16* __restrict__ Bf, __hip_bfloat16* __restrict__ W1f) {
    int idx = blockIdx.x * blockDim.x + threadIdx.x;
    const int nb = NT * KT * 512;
    if (idx < nb) {
        int j = idx & 7, L = (idx >> 3) & 63, kt = (idx >> 9) % KT, nt = idx / (KT * 512);
        int n = nt * 16 + (L & 15);
        int k = kt * 32 + ((L >> 4) << 3) + j;
        float acc = 0.f;
        if (n < NH && k < KX) {
            int u = k / IMG, v = k - u * IMG;
#pragma unroll
            for (int i = 0; i < 3; ++i)
#pragma unroll
                for (int jj = 0; jj < 3; ++jj) {
                    int r = u - i, c = v - jj;
                    if (r >= 0 && r < 26 && c >= 0 && c < 26)
                        acc += cw[i * 3 + jj] * w0[n * 676 + r * 26 + c];
                }
        }
        Bf[idx] = __float2bfloat16(acc);
    } else if (idx < nb + W1KT * 512) {
        int r = idx - nb;
        int j = r & 7, L = (r >> 3) & 63, kt = r >> 9;
        int n = L & 15, k = kt * 32 + ((L >> 4) << 3) + j;
        float v = (n < NOUT && k < NH) ? w1[n * NH + k] : 0.f;
        W1f[r] = __float2bfloat16(v);
    }
}

// --- one wave = 32 images, fully self-contained, NO barriers ---
__global__ __launch_bounds__(64, 1) void mlp_wave_kernel(
    const float* __restrict__ x,            // [32768, 784]
    const __hip_bfloat16* __restrict__ Bf,  // fragment-packed W_eff
    const __hip_bfloat16* __restrict__ W1f, // fragment-packed w1
    const float* __restrict__ b0,           // [200]
    const float* __restrict__ b1,           // [10]
    float* __restrict__ out)                // [32768, 10]
{
    __shared__ __hip_bfloat16 Hs[32 * HS];  // 14848 B, wave-private

    const int L  = threadIdx.x;
    const int lm = L & 15;
    const int q  = L >> 4;
    const size_t img0 = (size_t)blockIdx.x * 32;

    // zero h-pad cols 208..223 (read by FC1 kt=6; W1f there is 0 but LDS garbage could be NaN)
#pragma unroll
    for (int t = 0; t < 8; ++t) {
        int i = L + t * 64;                 // 512 = 32 rows x 16 cols
        Hs[(i >> 4) * HS + 208 + (i & 15)] = __float2bfloat16(0.f);
    }

    // ---- FC0: D[m][n] = sum_k x[m][k] * W_eff[n][k] ----
    f32x4 acc[2][NT];
#pragma unroll
    for (int m = 0; m < 2; ++m)
#pragma unroll
        for (int t = 0; t < NT; ++t) acc[m][t] = (f32x4){0.f, 0.f, 0.f, 0.f};

    const char* xrow0 = (const char*)(x + (img0 + lm) * KX);       // row lm
    const char* xrow1 = xrow0 + (size_t)16 * KX * 4;               // row lm+16
    const bf16x8* bb  = (const bf16x8*)Bf + L;

    for (int kt = 0; kt < KT; ++kt) {
        // lane's 8 floats of A: cols kt*32 + q*8 .. +7.  kt=24 cols>=784 are pad:
        // clamp address in-bounds; Bf is zero there so garbage contributes 0.
        const int qc = (kt == KT - 1) ? (q < 2 ? q : 1) : q;
        const int off = kt * 128 + qc * 32;
        float4 a0lo = *(const float4*)(xrow0 + off);
        float4 a0hi = *(const float4*)(xrow0 + off + 16);
        float4 a1lo = *(const float4*)(xrow1 + off);
        float4 a1hi = *(const float4*)(xrow1 + off + 16);
        bf16x8 af0 = cvt8(a0lo, a0hi);
        bf16x8 af1 = cvt8(a1lo, a1hi);
#pragma unroll
        for (int t = 0; t < NT; ++t) {
            bf16x8 bf = bb[(t * KT + kt) * 64];
            acc[0][t] = __builtin_amdgcn_mfma_f32_16x16x32_bf16(af0, bf, acc[0][t], 0, 0, 0);
            acc[1][t] = __builtin_amdgcn_mfma_f32_16x16x32_bf16(af1, bf, acc[1][t], 0, 0, 0);
        }
    }

    // ---- epilogue: h = relu(acc + b0) -> wave-private LDS (bf16, row-major) ----
#pragma unroll
    for (int t = 0; t < NT; ++t) {
        int n = t * 16 + lm;
        float bv = (n < NH) ? b0[n] : 0.f;
#pragma unroll
        for (int m = 0; m < 2; ++m) {
#pragma unroll
            for (int r = 0; r < 4; ++r) {
                float v = (n < NH) ? (acc[m][t][r] + bv) : 0.f;
                v = v > 0.f ? v : 0.f;
                Hs[(m * 16 + q * 4 + r) * HS + n] = __float2bfloat16(v);
            }
        }
    }
    // same wave reads its own writes: compiler inserts lgkmcnt wait; no barrier needed.

    // ---- FC1: out = h @ w1.T + b1 via MFMA over K=224 ----
    f32x4 o0 = (f32x4){0.f, 0.f, 0.f, 0.f};
    f32x4 o1 = (f32x4){0.f, 0.f, 0.f, 0.f};
    const bf16x8* w1b = (const bf16x8*)W1f + L;
#pragma unroll
    for (int kt = 0; kt < W1KT; ++kt) {
        bf16x8 bw = w1b[kt * 64];
        bf16x8 ah0 = *(const bf16x8*)(Hs + (lm)      * HS + kt * 32 + q * 8);
        bf16x8 ah1 = *(const bf16x8*)(Hs + (16 + lm) * HS + kt * 32 + q * 8);
        o0 = __builtin_amdgcn_mfma_f32_16x16x32_bf16(ah0, bw, o0, 0, 0, 0);
        o1 = __builtin_amdgcn_mfma_f32_16x16x32_bf16(ah1, bw, o1, 0, 0, 0);
    }
    if (lm < NOUT) {
        float bias = b1[lm];
#pragma unroll
        for (int r = 0; r < 4; ++r) {
            out[(img0 + q * 4 + r) * NOUT + lm]      = o0[r] + bias;
            out[(img0 + 16 + q * 4 + r) * NOUT + lm] = o1[r] + bias;
        }
    }
}

extern "C" void kernel_launch(void* const* d_in, const int* in_sizes, int n_in,
                              void* d_out, int out_size, void* d_ws, size_t ws_size,
                              hipStream_t stream) {
    const float* x   = (const float*)d_in[0];
    const float* cw  = (const float*)d_in[1];
    const float* w0  = (const float*)d_in[2];
    const float* b0  = (const float*)d_in[3];
    const float* w1  = (const float*)d_in[4];
    const float* b1  = (const float*)d_in[5];
    float* out = (float*)d_out;

    __hip_bfloat16* Bf  = (__hip_bfloat16*)d_ws;            // 13*25*512*2 = 332,800 B
    __hip_bfloat16* W1f = Bf + NT * KT * 512;               // 7*512*2 = 7,168 B

    const int pack_elems = NT * KT * 512 + W1KT * 512;
    build_weights<<<(pack_elems + 255) / 256, 256, 0, stream>>>(w0, cw, w1, Bf, W1f);

    mlp_wave_kernel<<<32768 / 32, 64, 0, stream>>>(x, Bf, W1f, b0, b1, out);
}

// Round 8
// 187.225 us; speedup vs baseline: 1.2710x; 1.2710x over previous
//
#include <hip/hip_runtime.h>
#include <hip/hip_bf16.h>

#define IMG 28
#define KX 784             // true K = 28*28
#define KT 25              // k-tiles of 32 -> K padded to 800
#define NT 13              // n-tiles of 16 -> N padded to 208
#define NH 200
#define NOUT 10
#define MT 32              // images per block
#define AS 808             // bf16 elems per LDS A row (800 + 8 pad)
#define HSTRIDE 208        // fp32 elems per LDS h row

typedef __attribute__((ext_vector_type(8))) short bf16x8;
typedef __attribute__((ext_vector_type(4))) float f32x4;
typedef __attribute__((ext_vector_type(4))) short s16x4;

static __device__ __forceinline__ unsigned short bf16_bits(float v) {
    __hip_bfloat16 b = __float2bfloat16(v);
    return *(unsigned short*)&b;
}

// --- build W_eff = w0 composed with conv, packed in MFMA fragment order ---
// Bf[nt][kt][lane][j] = W_eff[nt*16+(lane&15)][kt*32+(lane>>4)*8+j], 0-padded.
__global__ void build_weff(const float* __restrict__ w0, const float* __restrict__ cw,
                           __hip_bfloat16* __restrict__ Bf) {
    int idx = blockIdx.x * blockDim.x + threadIdx.x;
    if (idx >= NT * KT * 512) return;
    int j = idx & 7, L = (idx >> 3) & 63, kt = (idx >> 9) % KT, nt = idx / (KT * 512);
    int n = nt * 16 + (L & 15);
    int k = kt * 32 + ((L >> 4) << 3) + j;
    float acc = 0.f;
    if (n < NH && k < KX) {
        int u = k / IMG, v = k - u * IMG;
#pragma unroll
        for (int i = 0; i < 3; ++i) {
#pragma unroll
            for (int jj = 0; jj < 3; ++jj) {
                int r = u - i, c = v - jj;
                if (r >= 0 && r < 26 && c >= 0 && c < 26)
                    acc += cw[i * 3 + jj] * w0[n * 676 + r * 26 + c];
            }
        }
    }
    Bf[idx] = __float2bfloat16(acc);
}

// FC0 GEMM loop: both m-subs per wave, NTN n-tiles, B software-pipelined.
template <int NTN>
static __device__ __forceinline__ void gemm_loop(
    const __hip_bfloat16* __restrict__ a0p, const __hip_bfloat16* __restrict__ a1p,
    const bf16x8* __restrict__ bb, f32x4 acc[2][2])
{
    bf16x8 bc0 = bb[0];
    bf16x8 bc1 = (NTN == 2) ? bb[KT * 64] : bc0;
    for (int kt = 0; kt < KT; ++kt) {
        bf16x8 bn0 = bc0, bn1 = bc1;
        if (kt < KT - 1) {
            bn0 = bb[(kt + 1) * 64];
            if (NTN == 2) bn1 = bb[(KT + kt + 1) * 64];
        }
        bf16x8 af0 = *(const bf16x8*)(a0p + kt * 32);
        bf16x8 af1 = *(const bf16x8*)(a1p + kt * 32);
        acc[0][0] = __builtin_amdgcn_mfma_f32_16x16x32_bf16(af0, bc0, acc[0][0], 0, 0, 0);
        acc[1][0] = __builtin_amdgcn_mfma_f32_16x16x32_bf16(af1, bc0, acc[1][0], 0, 0, 0);
        if (NTN == 2) {
            acc[0][1] = __builtin_amdgcn_mfma_f32_16x16x32_bf16(af0, bc1, acc[0][1], 0, 0, 0);
            acc[1][1] = __builtin_amdgcn_mfma_f32_16x16x32_bf16(af1, bc1, acc[1][1], 0, 0, 0);
        }
        bc0 = bn0; bc1 = bn1;
    }
}

// launch_bounds (512,4): 128-VGPR cap so the 13 staging float4s stay in flight;
// 2 blocks/CU (103 KB LDS), 16 waves/CU.
__global__ __launch_bounds__(512, 4) void gemm_fused_kernel(
    const float* __restrict__ x,            // [32768, 784]
    const __hip_bfloat16* __restrict__ Bf,  // fragment-packed W_eff
    const float* __restrict__ b0,           // [200]
    const float* __restrict__ w1,           // [10, 200]
    const float* __restrict__ b1,           // [10]
    float* __restrict__ out)                // [32768, 10]
{
    __shared__ __align__(16) char lds_raw[MT * AS * 2];  // 51,712 B
    __hip_bfloat16* A = (__hip_bfloat16*)lds_raw;        // [MT][AS] bf16
    float* H = (float*)lds_raw;                          // [MT][HSTRIDE] fp32 overlay

    const int tid  = threadIdx.x;
    const int wave = tid >> 6;
    const int L    = tid & 63;
    const int lm   = L & 15;
    const int q    = L >> 4;
    const int img0 = blockIdx.x * MT;

    // ---- zero K-pad cols 784..799 (one short per thread: 32 rows x 16 cols) ----
    {
        int row = tid >> 4, c = KX + (tid & 15);
        ((unsigned short*)A)[row * AS + c] = 0;
    }

    // ---- stage x -> bf16 LDS A; 13 back-to-back float4 loads per lane, all live ----
    {
        const float4* xx = (const float4*)(x + (size_t)img0 * KX);  // 32*196 f4, contiguous
        float4 v[13];
#pragma unroll
        for (int t = 0; t < 13; ++t) {
            int f = tid + 512 * t;
            v[t] = (f < MT * 196) ? xx[f] : (float4){0.f, 0.f, 0.f, 0.f};
        }
#pragma unroll
        for (int t = 0; t < 13; ++t) {
            int f = tid + 512 * t;
            if (f < MT * 196) {
                int row  = f / 196;
                int col4 = f - row * 196;
                s16x4 p;
                p.x = (short)bf16_bits(v[t].x);
                p.y = (short)bf16_bits(v[t].y);
                p.z = (short)bf16_bits(v[t].z);
                p.w = (short)bf16_bits(v[t].w);
                *(s16x4*)(A + row * AS + col4 * 4) = p;
            }
        }
    }
    __syncthreads();

    // ---- FC0: 8 waves own disjoint n-tiles {2,2,2,2,2,1,1,1}, both m-subs each ----
    const int ntbase = (wave < 5) ? wave * 2 : 10 + (wave - 5);
    const int ntn    = (wave < 5) ? 2 : 1;

    f32x4 acc[2][2];
#pragma unroll
    for (int m = 0; m < 2; ++m)
#pragma unroll
        for (int t = 0; t < 2; ++t) acc[m][t] = (f32x4){0.f, 0.f, 0.f, 0.f};

    {
        const __hip_bfloat16* a0p = A + lm * AS + q * 8;
        const __hip_bfloat16* a1p = A + (16 + lm) * AS + q * 8;
        const bf16x8* bb = (const bf16x8*)Bf + (size_t)ntbase * KT * 64 + L;
        if (ntn == 2) gemm_loop<2>(a0p, a1p, bb, acc);
        else          gemm_loop<1>(a0p, a1p, bb, acc);
    }
    __syncthreads();  // done reading A before H overlay

    // ---- epilogue: h = relu(acc + b0) -> LDS ----
#pragma unroll
    for (int t = 0; t < 2; ++t) {
        if (t < ntn) {
            int n = (ntbase + t) * 16 + lm;
            if (n < NH) {
                float bv = b0[n];
#pragma unroll
                for (int m = 0; m < 2; ++m) {
#pragma unroll
                    for (int r = 0; r < 4; ++r) {
                        int mm = m * 16 + q * 4 + r;
                        float v = acc[m][t][r] + bv;
                        H[mm * HSTRIDE + n] = v > 0.f ? v : 0.f;
                    }
                }
            }
        }
    }
    __syncthreads();

    // ---- FC1: out = h @ w1.T + b1 (fp32 VALU, 320 results/block) ----
    if (tid < MT * NOUT) {
        int i = tid / NOUT;
        int j = tid - i * NOUT;
        const float4* hrow = (const float4*)(H + i * HSTRIDE);
        const float4* wrow = (const float4*)(w1 + j * NH);
        float s = b1[j];
        float4 accv = {0.f, 0.f, 0.f, 0.f};
#pragma unroll 10
        for (int n = 0; n < NH / 4; ++n) {
            float4 h4 = hrow[n];
            float4 w4 = wrow[n];
            accv.x += h4.x * w4.x;
            accv.y += h4.y * w4.y;
            accv.z += h4.z * w4.z;
            accv.w += h4.w * w4.w;
        }
        s += (accv.x + accv.y) + (accv.z + accv.w);
        out[(size_t)(img0 + i) * NOUT + j] = s;
    }
}

extern "C" void kernel_launch(void* const* d_in, const int* in_sizes, int n_in,
                              void* d_out, int out_size, void* d_ws, size_t ws_size,
                              hipStream_t stream) {
    const float* x   = (const float*)d_in[0];
    const float* cw  = (const float*)d_in[1];
    const float* w0  = (const float*)d_in[2];
    const float* b0  = (const float*)d_in[3];
    const float* w1  = (const float*)d_in[4];
    const float* b1  = (const float*)d_in[5];
    float* out = (float*)d_out;

    __hip_bfloat16* Bf = (__hip_bfloat16*)d_ws;  // 13*25*512*2 = 332,800 B

    const int pack_elems = NT * KT * 512;
    build_weff<<<(pack_elems + 255) / 256, 256, 0, stream>>>(w0, cw, Bf);

    gemm_fused_kernel<<<32768 / MT, 512, 0, stream>>>(x, Bf, b0, w1, b1, out);
}

// Round 9
// 186.876 us; speedup vs baseline: 1.2734x; 1.0019x over previous
//
#include <hip/hip_runtime.h>
#include <hip/hip_bf16.h>

#define IMG 28
#define KX 784             // true K = 28*28
#define KT 25              // k-tiles of 32 -> K padded to 800
#define NT 13              // n-tiles of 16 -> N padded to 208
#define NH 200
#define NOUT 10
#define MT 32              // images per block
#define AS 808             // bf16 elems per LDS A row (800 + 8 pad)
#define HSTRIDE 208        // fp32 elems per LDS h row

typedef __attribute__((ext_vector_type(8))) short bf16x8;
typedef __attribute__((ext_vector_type(4))) float f32x4;
typedef __attribute__((ext_vector_type(4))) short s16x4;

static __device__ __forceinline__ unsigned short bf16_bits(float v) {
    __hip_bfloat16 b = __float2bfloat16(v);
    return *(unsigned short*)&b;
}

// --- build W_eff = w0 composed with conv, packed in MFMA fragment order ---
// Bf[nt][kt][lane][j] = W_eff[nt*16+(lane&15)][kt*32+(lane>>4)*8+j], 0-padded.
__global__ void build_weff(const float* __restrict__ w0, const float* __restrict__ cw,
                           __hip_bfloat16* __restrict__ Bf) {
    int idx = blockIdx.x * blockDim.x + threadIdx.x;
    if (idx >= NT * KT * 512) return;
    int j = idx & 7, L = (idx >> 3) & 63, kt = (idx >> 9) % KT, nt = idx / (KT * 512);
    int n = nt * 16 + (L & 15);
    int k = kt * 32 + ((L >> 4) << 3) + j;
    float acc = 0.f;
    if (n < NH && k < KX) {
        int u = k / IMG, v = k - u * IMG;
#pragma unroll
        for (int i = 0; i < 3; ++i) {
#pragma unroll
            for (int jj = 0; jj < 3; ++jj) {
                int r = u - i, c = v - jj;
                if (r >= 0 && r < 26 && c >= 0 && c < 26)
                    acc += cw[i * 3 + jj] * w0[n * 676 + r * 26 + c];
            }
        }
    }
    Bf[idx] = __float2bfloat16(acc);
}

// FC0 GEMM loop: both m-subs per wave, NTN n-tiles, B prefetched at distance 4.
// p0/p1 arrive preloaded with kt=0..3 (issued before the staging barrier).
template <int NTN>
static __device__ __forceinline__ void gemm_loop(
    const __hip_bfloat16* __restrict__ a0p, const __hip_bfloat16* __restrict__ a1p,
    const bf16x8* __restrict__ bb, bf16x8 p0[4], bf16x8 p1[4], f32x4 acc[2][2])
{
#pragma unroll
    for (int kt = 0; kt < KT; ++kt) {
        const int slot = kt & 3;
        bf16x8 b0 = p0[slot];
        bf16x8 b1 = p1[slot];
        if (kt + 4 < KT) {
            p0[slot] = bb[(kt + 4) * 64];
            if (NTN == 2) p1[slot] = bb[(KT + kt + 4) * 64];
        }
        bf16x8 af0 = *(const bf16x8*)(a0p + kt * 32);
        bf16x8 af1 = *(const bf16x8*)(a1p + kt * 32);
        acc[0][0] = __builtin_amdgcn_mfma_f32_16x16x32_bf16(af0, b0, acc[0][0], 0, 0, 0);
        acc[1][0] = __builtin_amdgcn_mfma_f32_16x16x32_bf16(af1, b0, acc[1][0], 0, 0, 0);
        if (NTN == 2) {
            acc[0][1] = __builtin_amdgcn_mfma_f32_16x16x32_bf16(af0, b1, acc[0][1], 0, 0, 0);
            acc[1][1] = __builtin_amdgcn_mfma_f32_16x16x32_bf16(af1, b1, acc[1][1], 0, 0, 0);
        }
    }
}

// (512,4): 128-VGPR cap, 2 blocks/CU (103 KB LDS), 16 waves/CU.
__global__ __launch_bounds__(512, 4) void gemm_fused_kernel(
    const float* __restrict__ x,            // [32768, 784]
    const __hip_bfloat16* __restrict__ Bf,  // fragment-packed W_eff
    const float* __restrict__ b0,           // [200]
    const float* __restrict__ w1,           // [10, 200]
    const float* __restrict__ b1,           // [10]
    float* __restrict__ out)                // [32768, 10]
{
    __shared__ __align__(16) char lds_raw[MT * AS * 2];  // 51,712 B
    __hip_bfloat16* A = (__hip_bfloat16*)lds_raw;        // [MT][AS] bf16
    float* H = (float*)lds_raw;                          // [MT][HSTRIDE] fp32 overlay

    const int tid  = threadIdx.x;
    const int wave = tid >> 6;
    const int L    = tid & 63;
    const int lm   = L & 15;
    const int q    = L >> 4;
    const int img0 = blockIdx.x * MT;

    // ---- zero K-pad cols 784..799 (one short per thread: 32 rows x 16 cols) ----
    {
        int row = tid >> 4, c = KX + (tid & 15);
        ((unsigned short*)A)[row * AS + c] = 0;
    }

    // ---- stage x -> bf16 LDS A; sched_barrier(0) forces all 13 loads in flight ----
    {
        const float4* xx = (const float4*)(x + (size_t)img0 * KX);  // 32*196 f4, contiguous
        float4 v[13];
#pragma unroll
        for (int t = 0; t < 13; ++t) {
            int f = tid + 512 * t;
            v[t] = (f < MT * 196) ? xx[f] : (float4){0.f, 0.f, 0.f, 0.f};
        }
        __builtin_amdgcn_sched_barrier(0);   // opaque fence: no load/store fusion across
#pragma unroll
        for (int t = 0; t < 13; ++t) {
            int f = tid + 512 * t;
            if (f < MT * 196) {
                int row  = f / 196;
                int col4 = f - row * 196;
                s16x4 p;
                p.x = (short)bf16_bits(v[t].x);
                p.y = (short)bf16_bits(v[t].y);
                p.z = (short)bf16_bits(v[t].z);
                p.w = (short)bf16_bits(v[t].w);
                *(s16x4*)(A + row * AS + col4 * 4) = p;
            }
        }
    }

    // ---- n-tile ownership: waves {2,2,2,2,2,1,1,1} ----
    const int ntbase = (wave < 5) ? wave * 2 : 10 + (wave - 5);
    const int ntn    = (wave < 5) ? 2 : 1;
    const bf16x8* bb = (const bf16x8*)Bf + (size_t)ntbase * KT * 64 + L;

    // ---- preload B kt=0..3 BEFORE the barrier: latency hides under the drain ----
    bf16x8 p0[4], p1[4];
#pragma unroll
    for (int d = 0; d < 4; ++d) {
        p0[d] = bb[d * 64];
        p1[d] = (ntn == 2) ? bb[(KT + d) * 64] : p0[d];
    }
    __syncthreads();

    f32x4 acc[2][2];
#pragma unroll
    for (int m = 0; m < 2; ++m)
#pragma unroll
        for (int t = 0; t < 2; ++t) acc[m][t] = (f32x4){0.f, 0.f, 0.f, 0.f};

    {
        const __hip_bfloat16* a0p = A + lm * AS + q * 8;
        const __hip_bfloat16* a1p = A + (16 + lm) * AS + q * 8;
        if (ntn == 2) gemm_loop<2>(a0p, a1p, bb, p0, p1, acc);
        else          gemm_loop<1>(a0p, a1p, bb, p0, p1, acc);
    }
    __syncthreads();  // done reading A before H overlay

    // ---- epilogue: h = relu(acc + b0) -> LDS ----
#pragma unroll
    for (int t = 0; t < 2; ++t) {
        if (t < ntn) {
            int n = (ntbase + t) * 16 + lm;
            if (n < NH) {
                float bv = b0[n];
#pragma unroll
                for (int m = 0; m < 2; ++m) {
#pragma unroll
                    for (int r = 0; r < 4; ++r) {
                        int mm = m * 16 + q * 4 + r;
                        float v = acc[m][t][r] + bv;
                        H[mm * HSTRIDE + n] = v > 0.f ? v : 0.f;
                    }
                }
            }
        }
    }
    __syncthreads();

    // ---- FC1: out = h @ w1.T + b1 (fp32 VALU, 320 results/block) ----
    if (tid < MT * NOUT) {
        int i = tid / NOUT;
        int j = tid - i * NOUT;
        const float4* hrow = (const float4*)(H + i * HSTRIDE);
        const float4* wrow = (const float4*)(w1 + j * NH);
        float s = b1[j];
        float4 accv = {0.f, 0.f, 0.f, 0.f};
#pragma unroll 10
        for (int n = 0; n < NH / 4; ++n) {
            float4 h4 = hrow[n];
            float4 w4 = wrow[n];
            accv.x += h4.x * w4.x;
            accv.y += h4.y * w4.y;
            accv.z += h4.z * w4.z;
            accv.w += h4.w * w4.w;
        }
        s += (accv.x + accv.y) + (accv.z + accv.w);
        out[(size_t)(img0 + i) * NOUT + j] = s;
    }
}

extern "C" void kernel_launch(void* const* d_in, const int* in_sizes, int n_in,
                              void* d_out, int out_size, void* d_ws, size_t ws_size,
                              hipStream_t stream) {
    const float* x   = (const float*)d_in[0];
    const float* cw  = (const float*)d_in[1];
    const float* w0  = (const float*)d_in[2];
    const float* b0  = (const float*)d_in[3];
    const float* w1  = (const float*)d_in[4];
    const float* b1  = (const float*)d_in[5];
    float* out = (float*)d_out;

    __hip_bfloat16* Bf = (__hip_bfloat16*)d_ws;  // 13*25*512*2 = 332,800 B

    const int pack_elems = NT * KT * 512;
    build_weff<<<(pack_elems + 255) / 256, 256, 0, stream>>>(w0, cw, Bf);

    gemm_fused_kernel<<<32768 / MT, 512, 0, stream>>>(x, Bf, b0, w1, b1, out);
}